// Round 7
// baseline (342.614 us; speedup 1.0000x reference)
//
#include <hip/hip_runtime.h>

// VQ-VAE vector quantization for z:(32,256,32,32) f32, codebook:(1024,256) f32.
// Outputs (flat f32 in d_out): z_q (B,C,H,W) [8388608] | loss [1] | indices as float [32768].
//
// Round 7: pipelined argmin. Round-6: MfmaUtil 25% == MFMA floor (20.6us) but
// 81us total -> 75% pipeline exposure (2-barrier lockstep staging + imbalanced
// LDS bank pattern, conflicts 9.4M). Changes:
//   - combined 128B LDS rows (hi|lo granules) + XOR swizzle g^=(row&7): with
//     128B rows bank depends only on granule, XOR balances 8 lanes/position
//     for BOTH frag reads and staging writes -> conflict-free.
//   - 2-phase double-buffer, 1 barrier/step: issue loads(s+1) -> MFMA(s) ->
//     ds_write(s+1) -> barrier. Load latency hides under 48 MFMA.
//   - cbsplit/prep emit combined pre-layouts (cbs[kc][code][64] in d_ws,
//     zsc[kc][n][64] in the z_q region, exact byte fit).
// Verified top-2 / merge / exact-fp32-fallback / gather kept verbatim.

#define EDIM   256
#define NCODE  1024
#define HWSZ   1024
#define NPIX   32768
#define LOSS_OFF 8388608
#define IDX_OFF  8388609
#define THR    0.05f

typedef __attribute__((ext_vector_type(8))) short s16x8;   // 8 bf16 = 4 VGPR (MFMA A/B frag)
typedef __attribute__((ext_vector_type(4))) float f32x4;   // MFMA C/D frag

__device__ inline unsigned short f2bf(float f) {           // RNE f32 -> bf16
    unsigned u = __float_as_uint(f);
    return (unsigned short)((u + 0x7FFFu + ((u >> 16) & 1u)) >> 16);
}
__device__ inline float bf2f(unsigned short h) { return __uint_as_float(((unsigned)h) << 16); }

// ---------------------------------------------------------------------------
// Kernel 0: one-time codebook split -> combined layout cbs[kc][code][64]:
// granule g(16B)=k 8-elems; g 0-3 = hi(k=kc*32+g*8..), g 4-7 = lo. + exact norms.
__global__ __launch_bounds__(256) void vq_cbsplit(const float* __restrict__ cb,
                                                  unsigned short* __restrict__ cbs,
                                                  float* __restrict__ cnorm)
{
    const int t    = threadIdx.x;
    const int code = (blockIdx.x << 3) + (t >> 5);
    const int kg   = t & 31;                  // k = kg*8 .. kg*8+7
    const float4 v0 = *(const float4*)(cb + (size_t)code * EDIM + (kg << 3));
    const float4 v1 = *(const float4*)(cb + (size_t)code * EDIM + (kg << 3) + 4);

    float s = v0.x*v0.x + v0.y*v0.y + v0.z*v0.z + v0.w*v0.w
            + v1.x*v1.x + v1.y*v1.y + v1.z*v1.z + v1.w*v1.w;
    s += __shfl_xor(s, 1, 64);  s += __shfl_xor(s, 2, 64);
    s += __shfl_xor(s, 4, 64);  s += __shfl_xor(s, 8, 64);
    s += __shfl_xor(s, 16, 64);                 // sum over the code's 32 lanes
    if (kg == 0) cnorm[code] = s;

    const float f[8] = {v0.x, v0.y, v0.z, v0.w, v1.x, v1.y, v1.z, v1.w};
    unsigned short h[8], l[8];
#pragma unroll
    for (int j = 0; j < 8; ++j) { h[j] = f2bf(f[j]); l[j] = f2bf(f[j] - bf2f(h[j])); }
    uint4 H, L;
    H.x = (unsigned)h[0] | ((unsigned)h[1] << 16);  H.y = (unsigned)h[2] | ((unsigned)h[3] << 16);
    H.z = (unsigned)h[4] | ((unsigned)h[5] << 16);  H.w = (unsigned)h[6] | ((unsigned)h[7] << 16);
    L.x = (unsigned)l[0] | ((unsigned)l[1] << 16);  L.y = (unsigned)l[2] | ((unsigned)l[3] << 16);
    L.z = (unsigned)l[4] | ((unsigned)l[5] << 16);  L.w = (unsigned)l[6] | ((unsigned)l[7] << 16);
    // kc = kg>>2, granule = kg&3 (hi) / +4 (lo)
    const size_t off = ((size_t)(kg >> 2) * NCODE + code) * 64 + ((size_t)(kg & 3) << 3);
    *(uint4*)(cbs + off)      = H;            // hi granule
    *(uint4*)(cbs + off + 32) = L;            // lo granule (+4 granules)
}

// ---------------------------------------------------------------------------
// Kernel 1: transpose z -> combined zsc[kc][n][64] (granules: 0-3 hi, 4-7 lo).
// Also zeroes the loss slot. zsc fills the z_q output region byte-exactly.
__global__ __launch_bounds__(256) void vq_prep(const float* __restrict__ z,
                                               unsigned short* __restrict__ zsc,
                                               float* __restrict__ loss_slot)
{
    __shared__ unsigned lzp[64][68];          // packed hi|lo<<16, 64 px x 64 k slab

    const int t  = threadIdx.x;
    const int n0 = blockIdx.x << 6;           // 512 blocks x 64 px
    const int bb = n0 >> 10, hw0 = n0 & 1023;
    if (blockIdx.x == 0 && t == 0) *loss_slot = 0.0f;
    const float* zb = z + (size_t)bb * (EDIM * HWSZ) + hw0;

    for (int pk = 0; pk < 4; ++pk) {          // 4 k-slabs of 64
#pragma unroll
        for (int i = 0; i < 4; ++i) {         // 64k x 64px = 1024 float4
            const int linear = (i << 8) + t;
            const int kk  = linear >> 4;
            const int px4 = (linear & 15) << 2;
            const float4 v = *reinterpret_cast<const float4*>(zb + (pk * 64 + kk) * HWSZ + px4);
            const float vv[4] = {v.x, v.y, v.z, v.w};
#pragma unroll
            for (int j = 0; j < 4; ++j) {
                const unsigned short h = f2bf(vv[j]);
                const unsigned short l = f2bf(vv[j] - bf2f(h));
                lzp[px4 + j][kk] = (unsigned)h | ((unsigned)l << 16);
            }
        }
        __syncthreads();
        {
            const int px = t >> 2, q = t & 3;
            const int kq16 = q << 4;                      // 16 k per thread
            const uint4 q0 = *(const uint4*)&lzp[px][kq16];
            const uint4 q1 = *(const uint4*)&lzp[px][kq16 + 4];
            const uint4 q2 = *(const uint4*)&lzp[px][kq16 + 8];
            const uint4 q3 = *(const uint4*)&lzp[px][kq16 + 12];
            #define PH(a,b) (((a) & 0xffffu) | ((b) << 16))
            #define PL(a,b) (((a) >> 16) | ((b) & 0xffff0000u))
            const uint4 hA = {PH(q0.x,q0.y), PH(q0.z,q0.w), PH(q1.x,q1.y), PH(q1.z,q1.w)};
            const uint4 hB = {PH(q2.x,q2.y), PH(q2.z,q2.w), PH(q3.x,q3.y), PH(q3.z,q3.w)};
            const uint4 lA = {PL(q0.x,q0.y), PL(q0.z,q0.w), PL(q1.x,q1.y), PL(q1.z,q1.w)};
            const uint4 lB = {PL(q2.x,q2.y), PL(q2.z,q2.w), PL(q3.x,q3.y), PL(q3.z,q3.w)};
            #undef PH
            #undef PL
            const int kc = (pk << 1) + (q >> 1);          // k-chunk of 32
            const int ga = (q & 1) << 1;                  // hi granule base 0 or 2
            const size_t off = ((size_t)kc * NPIX + n0 + px) * 64 + ((size_t)ga << 3);
            *(uint4*)(zsc + off)      = hA;               // granule ga
            *(uint4*)(zsc + off + 8)  = hB;               // granule ga+1
            *(uint4*)(zsc + off + 32) = lA;               // granule ga+4
            *(uint4*)(zsc + off + 40) = lB;               // granule ga+5
        }
        __syncthreads();
    }
}

// ---------------------------------------------------------------------------
// Kernel 2: pipelined MFMA distance GEMM + exact argmin.
// Block = 256 thr (4 waves) x 64 px x 1024 codes; 32 steps (4 groups x 8 kc),
// double-buffered LDS (swizzled 128B rows), 1 barrier/step.
__global__ __launch_bounds__(256) void vq_argmin_sw(
    const float* __restrict__ z, const float* __restrict__ cb,
    const unsigned short* __restrict__ zsc, const unsigned short* __restrict__ cbs,
    const float* __restrict__ cnorm, float* __restrict__ idx_out)
{
    __shared__ unsigned short cbt[2][256 * 64];  // 64 KiB
    __shared__ unsigned short ztl[2][64 * 64];   // 16 KiB
    __shared__ float cn[NCODE];                  // 4 KiB
    __shared__ float rb1[4][64], rb2[4][64];
    __shared__ int   ri1[4][64], ri2[4][64];
    __shared__ int   fl_cnt, fl_px[64], fl_i1[64], fl_i2[64];
    __shared__ float fred[2][4];

    const int t    = threadIdx.x;
    const int lane = t & 63;
    const int w    = t >> 6;
    const int n0   = blockIdx.x << 6;            // 512 blocks
    const int bb   = n0 >> 10, hw0 = n0 & 1023;
    const int l15  = lane & 15, kq = lane >> 4;
    const int swz  = (kq ^ (l15 & 7)) << 3;      // hi-granule ushort offset in row

    const int rz = t & 63;                       // z staging row (thread stages cb row t)
    const int ck = t & 7;                        // swizzle key for row t (== rz&7)

#pragma unroll
    for (int i = 0; i < 4; ++i) cn[(i << 8) + t] = cnorm[(i << 8) + t];
    if (t == 0) fl_cnt = 0;

    uint4 rg[8], rzv[2];
    auto do_loads = [&](int S) {                 // fetch step S into regs
        const int g_ = S >> 3, kc_ = S & 7;
        const uint4* cbase = (const uint4*)(cbs + (((size_t)kc_ * NCODE + (g_ << 8) + t) << 6));
#pragma unroll
        for (int j = 0; j < 8; ++j) rg[j] = cbase[j];
        const uint4* zbase = (const uint4*)(zsc + (((size_t)kc_ * NPIX + n0 + rz) << 6));
        rzv[0] = zbase[w];
        rzv[1] = zbase[w + 4];
    };
    auto do_writes = [&](int B) {                // regs -> swizzled LDS buffer B
        uint4* cd = (uint4*)&cbt[B][t << 6];
#pragma unroll
        for (int j = 0; j < 8; ++j) cd[j ^ ck] = rg[j];
        uint4* zd = (uint4*)&ztl[B][rz << 6];
        zd[w ^ ck]       = rzv[0];
        zd[(w + 4) ^ ck] = rzv[1];
    };

    float b1[4], b2[4]; int i1[4], i2[4];
#pragma unroll
    for (int nf = 0; nf < 4; ++nf) { b1[nf] = 3.402823e38f; b2[nf] = 3.402823e38f; i1[nf] = 0; i2[nf] = 0; }

    f32x4 acc[4][4];

    do_loads(0);
    do_writes(0);
    __syncthreads();

    for (int s = 0; s < 32; ++s) {
        const int buf = s & 1, g = s >> 3, kc = s & 7;
        if (kc == 0) {
#pragma unroll
            for (int mf = 0; mf < 4; ++mf)
#pragma unroll
                for (int nf = 0; nf < 4; ++nf) acc[mf][nf] = (f32x4){0.f, 0.f, 0.f, 0.f};
        }
        if (s < 31) do_loads(s + 1);             // issue early: latency hides under MFMA

        s16x8 ah[4], al[4], bh[4], bl[4];
#pragma unroll
        for (int mf = 0; mf < 4; ++mf) {
            const int ro = ((w << 6) + (mf << 4) + l15) << 6;
            ah[mf] = *(const s16x8*)&cbt[buf][ro + swz];
            al[mf] = *(const s16x8*)&cbt[buf][ro + (swz ^ 32)];
        }
#pragma unroll
        for (int nf = 0; nf < 4; ++nf) {
            const int ro = ((nf << 4) + l15) << 6;
            bh[nf] = *(const s16x8*)&ztl[buf][ro + swz];
            bl[nf] = *(const s16x8*)&ztl[buf][ro + (swz ^ 32)];
        }
#pragma unroll
        for (int mf = 0; mf < 4; ++mf)
#pragma unroll
            for (int nf = 0; nf < 4; ++nf)
                acc[mf][nf] = __builtin_amdgcn_mfma_f32_16x16x32_bf16(ah[mf], bh[nf], acc[mf][nf], 0, 0, 0);
#pragma unroll
        for (int mf = 0; mf < 4; ++mf)
#pragma unroll
            for (int nf = 0; nf < 4; ++nf)
                acc[mf][nf] = __builtin_amdgcn_mfma_f32_16x16x32_bf16(ah[mf], bl[nf], acc[mf][nf], 0, 0, 0);
#pragma unroll
        for (int mf = 0; mf < 4; ++mf)
#pragma unroll
            for (int nf = 0; nf < 4; ++nf)
                acc[mf][nf] = __builtin_amdgcn_mfma_f32_16x16x32_bf16(al[mf], bh[nf], acc[mf][nf], 0, 0, 0);

        if (kc == 7) {
            // top-2 update. D layout: col(px)=lane&15, row=(lane>>4)*4+r.
#pragma unroll
            for (int mf = 0; mf < 4; ++mf)
#pragma unroll
                for (int r = 0; r < 4; ++r) {
                    const int local = (w << 6) + (mf << 4) + (kq << 2) + r;
                    const int code  = (g << 8) + local;     // ascending per lane
                    const float cnv = cn[code];
#pragma unroll
                    for (int nf = 0; nf < 4; ++nf) {
                        const float d = fmaf(-2.f, acc[mf][nf][r], cnv);
                        if (d < b1[nf])      { b2[nf] = b1[nf]; i2[nf] = i1[nf]; b1[nf] = d; i1[nf] = code; }
                        else if (d < b2[nf]) { b2[nf] = d; i2[nf] = code; }
                    }
                }
        }
        if (s < 31) do_writes(buf ^ 1);          // compiler waits vmcnt for rg/rzv
        __syncthreads();                          // writes visible; reads of buf done
    }

    // ---- cross-lane merge (lanes p, p+16, p+32, p+48 share pixel col p)
#pragma unroll
    for (int nf = 0; nf < 4; ++nf) {
        float B1 = b1[nf], B2 = b2[nf]; int I1 = i1[nf], I2 = i2[nf];
#pragma unroll
        for (int m = 16; m <= 32; m <<= 1) {
            const float ob1 = __shfl_xor(B1, m, 64), ob2 = __shfl_xor(B2, m, 64);
            const int   oi1 = __shfl_xor(I1, m, 64), oi2 = __shfl_xor(I2, m, 64);
            if (ob1 < B1 || (ob1 == B1 && oi1 < I1)) {
                if (B1 < ob2 || (B1 == ob2 && I1 < oi2)) { B2 = B1; I2 = I1; }
                else                                      { B2 = ob2; I2 = oi2; }
                B1 = ob1; I1 = oi1;
            } else if (ob1 < B2 || (ob1 == B2 && oi1 < I2)) { B2 = ob1; I2 = oi1; }
        }
        if (lane < 16) {
            const int px = (nf << 4) + lane;
            rb1[w][px] = B1; rb2[w][px] = B2; ri1[w][px] = I1; ri2[w][px] = I2;
        }
    }
    __syncthreads();
    if (t < 64) {
        float B1 = rb1[0][t], B2 = rb2[0][t]; int I1 = ri1[0][t], I2 = ri2[0][t];
#pragma unroll
        for (int ww = 1; ww < 4; ++ww) {
            const float ob1 = rb1[ww][t], ob2 = rb2[ww][t];
            const int   oi1 = ri1[ww][t], oi2 = ri2[ww][t];
            if (ob1 < B1 || (ob1 == B1 && oi1 < I1)) {
                if (B1 < ob2 || (B1 == ob2 && I1 < oi2)) { B2 = B1; I2 = I1; }
                else                                      { B2 = ob2; I2 = oi2; }
                B1 = ob1; I1 = oi1;
            } else if (ob1 < B2 || (ob1 == B2 && oi1 < I2)) { B2 = ob1; I2 = oi1; }
        }
        if (B2 - B1 > THR) idx_out[n0 + t] = (float)I1;   // provably exact
        else {
            const int pos = atomicAdd(&fl_cnt, 1);
            fl_px[pos] = t; fl_i1[pos] = I1; fl_i2[pos] = I2;
        }
    }
    __syncthreads();
    // ---- exact fp32 fallback for near-tie pixels (expected ~1-2 per block)
    const int nfl = fl_cnt;
    for (int fi = 0; fi < nfl; ++fi) {
        const int px = fl_px[fi], ia = fl_i1[fi], ib = fl_i2[fi];
        const float zk = z[(size_t)bb * (EDIM * HWSZ) + t * HWSZ + hw0 + px];  // k = t
        const float da = zk - cb[(size_t)ia * EDIM + t];
        const float db = zk - cb[(size_t)ib * EDIM + t];
        float s1 = da * da, s2 = db * db;
#pragma unroll
        for (int m = 32; m; m >>= 1) { s1 += __shfl_xor(s1, m, 64); s2 += __shfl_xor(s2, m, 64); }
        if (lane == 0) { fred[0][w] = s1; fred[1][w] = s2; }
        __syncthreads();
        if (t == 0) {
            const float d1 = fred[0][0] + fred[0][1] + fred[0][2] + fred[0][3];
            const float d2 = fred[1][0] + fred[1][1] + fred[1][2] + fred[1][3];
            const int win = (d2 < d1 || (d2 == d1 && ib < ia)) ? ib : ia;
            idx_out[n0 + px] = (float)win;
        }
        __syncthreads();
    }
}

// ---------------------------------------------------------------------------
// Kernel 3: gather z_q = codebook[idx], transpose-store to (B,C,H,W), fused
// MSE loss: codebook_loss = (1 + BETA) * mean((z_q - z)^2), BETA = 0.25.
__global__ __launch_bounds__(256) void vq_gather(const float* __restrict__ z,
                                                 const float* __restrict__ cb,
                                                 const float* __restrict__ idxf,
                                                 float* __restrict__ out)
{
    __shared__ float lq[64][129];
    __shared__ int   sidx[64];

    const int t   = threadIdx.x;
    const int n0  = blockIdx.x << 6;
    const int bb  = n0 >> 10;
    const int hw0 = n0 & 1023;

    if (t < 64) sidx[t] = (int)idxf[n0 + t];

    const float* zb = z   + (size_t)bb * (EDIM * HWSZ) + hw0;
    float*       ob = out + (size_t)bb * (EDIM * HWSZ) + hw0;
    const int p  = t & 63;
    const int cq = t >> 6;
    float sum = 0.0f;

    for (int h = 0; h < 2; ++h) {
        __syncthreads();
#pragma unroll
        for (int i = 0; i < 8; ++i) {
            const int linear = (i << 8) + t;
            const int pr = linear >> 5;
            const int f4 = (linear & 31) << 2;
            const float4 v = *reinterpret_cast<const float4*>(
                cb + (size_t)sidx[pr] * EDIM + (h << 7) + f4);
            float* dst = &lq[pr][f4];
            dst[0] = v.x; dst[1] = v.y; dst[2] = v.z; dst[3] = v.w;
        }
        __syncthreads();
#pragma unroll 4
        for (int r = 0; r < 32; ++r) {
            const int c  = (r << 2) + cq;
            const int cf = (h << 7) + c;
            const float q  = lq[p][c];
            const float zv = zb[cf * HWSZ + p];
            ob[cf * HWSZ + p] = q;
            const float dd = q - zv;
            sum = fmaf(dd, dd, sum);
        }
    }

#pragma unroll
    for (int m = 32; m; m >>= 1) sum += __shfl_xor(sum, m, 64);
    if (p == 0) atomicAdd(out + LOSS_OFF, sum * (1.25f / 8388608.0f));
}

// ---------------------------------------------------------------------------
extern "C" void kernel_launch(void* const* d_in, const int* in_sizes, int n_in,
                              void* d_out, int out_size, void* d_ws, size_t ws_size,
                              hipStream_t stream)
{
    const float* z  = (const float*)d_in[0];
    const float* cb = (const float*)d_in[1];
    float* out = (float*)d_out;
    // zsc (combined z bf16 hi/lo) fills the z_q region byte-exactly (33.5 MB);
    // consumed by vq_argmin_sw, then overwritten by vq_gather.
    unsigned short* zsc = (unsigned short*)out;
    // d_ws: cbs (1 MB) | cnorm (4 KB). ws_size >= 1.05 MB established in round 6
    // (fast path dispatched with identical requirement).
    unsigned short* cbs = (unsigned short*)d_ws;
    float*          cnp = (float*)(cbs + (size_t)8 * NCODE * 64);

    vq_cbsplit  <<<NCODE / 8, 256, 0, stream>>>(cb, cbs, cnp);
    vq_prep     <<<NPIX / 64, 256, 0, stream>>>(z, zsc, out + LOSS_OFF);
    vq_argmin_sw<<<NPIX / 64, 256, 0, stream>>>(z, cb, zsc, cbs, cnp, out + IDX_OFF);
    vq_gather   <<<NPIX / 64, 256, 0, stream>>>(z, cb, out + IDX_OFF, out);
}

// Round 8
// 203.440 us; speedup vs baseline: 1.6841x; 1.6841x over previous
//
#include <hip/hip_runtime.h>

// VQ-VAE vector quantization for z:(32,256,32,32) f32, codebook:(1024,256) f32.
// Outputs (flat f32 in d_out): z_q (B,C,H,W) [8388608] | loss [1] | indices as float [32768].
//
// Round 8: revert round-7 pipeline (1 blk/CU + conflicts -> 228us). Base is
// round-6 (81us), which was LDS-PIPE-BOUND 3.4x (104 KB LDS traffic per 240-cy
// MFMA step). Fix = eliminate LDS traffic, not reschedule it:
//   - codebook A-frags load DIRECTLY global->VGPR from pre-split cbs
//     (16B/lane contiguous, wave covers 16x128B exactly), double-buffered
//     across steps -> no cb LDS writes/reads, NO main-loop barriers.
//   - z staged once in prologue into zh/zl[8][64][32] (64-B rows: reads are
//     8-addrs-per-16B-slot = proven conflict-free profile). Main loop: 8
//     ds_read_b128 + 48 MFMA per step, read-only LDS.
//   - LDS 73 KB -> 2 blocks/CU; launch_bounds(256,2) for ~200 VGPRs.
// cbsplit / top-2 / merge / exact-fp32-fallback / gather verbatim from round 6.

#define EDIM   256
#define NCODE  1024
#define HWSZ   1024
#define NPIX   32768
#define LOSS_OFF 8388608
#define IDX_OFF  8388609
#define THR    0.05f

typedef __attribute__((ext_vector_type(8))) short s16x8;   // 8 bf16 = 4 VGPR (MFMA A/B frag)
typedef __attribute__((ext_vector_type(4))) float f32x4;   // MFMA C/D frag

__device__ inline unsigned short f2bf(float f) {           // RNE f32 -> bf16
    unsigned u = __float_as_uint(f);
    return (unsigned short)((u + 0x7FFFu + ((u >> 16) & 1u)) >> 16);
}
__device__ inline float bf2f(unsigned short h) { return __uint_as_float(((unsigned)h) << 16); }

// ---------------------------------------------------------------------------
// Kernel 0: one-time codebook split -> cbs[kc][code][64]: granule g(16B) =
// 8 k-elems; g 0-3 = hi(k=kc*32+g*8..), g 4-7 = lo. + exact f32 norms.
__global__ __launch_bounds__(256) void vq_cbsplit(const float* __restrict__ cb,
                                                  unsigned short* __restrict__ cbs,
                                                  float* __restrict__ cnorm)
{
    const int t    = threadIdx.x;
    const int code = (blockIdx.x << 3) + (t >> 5);
    const int kg   = t & 31;                  // k = kg*8 .. kg*8+7
    const float4 v0 = *(const float4*)(cb + (size_t)code * EDIM + (kg << 3));
    const float4 v1 = *(const float4*)(cb + (size_t)code * EDIM + (kg << 3) + 4);

    float s = v0.x*v0.x + v0.y*v0.y + v0.z*v0.z + v0.w*v0.w
            + v1.x*v1.x + v1.y*v1.y + v1.z*v1.z + v1.w*v1.w;
    s += __shfl_xor(s, 1, 64);  s += __shfl_xor(s, 2, 64);
    s += __shfl_xor(s, 4, 64);  s += __shfl_xor(s, 8, 64);
    s += __shfl_xor(s, 16, 64);                 // sum over the code's 32 lanes
    if (kg == 0) cnorm[code] = s;

    const float f[8] = {v0.x, v0.y, v0.z, v0.w, v1.x, v1.y, v1.z, v1.w};
    unsigned short h[8], l[8];
#pragma unroll
    for (int j = 0; j < 8; ++j) { h[j] = f2bf(f[j]); l[j] = f2bf(f[j] - bf2f(h[j])); }
    uint4 H, L;
    H.x = (unsigned)h[0] | ((unsigned)h[1] << 16);  H.y = (unsigned)h[2] | ((unsigned)h[3] << 16);
    H.z = (unsigned)h[4] | ((unsigned)h[5] << 16);  H.w = (unsigned)h[6] | ((unsigned)h[7] << 16);
    L.x = (unsigned)l[0] | ((unsigned)l[1] << 16);  L.y = (unsigned)l[2] | ((unsigned)l[3] << 16);
    L.z = (unsigned)l[4] | ((unsigned)l[5] << 16);  L.w = (unsigned)l[6] | ((unsigned)l[7] << 16);
    const size_t off = ((size_t)(kg >> 2) * NCODE + code) * 64 + ((size_t)(kg & 3) << 3);
    *(uint4*)(cbs + off)      = H;            // hi granule
    *(uint4*)(cbs + off + 32) = L;            // lo granule (+4 granules)
}

// ---------------------------------------------------------------------------
// Kernel 1: transpose z -> bf16 planes zscH[kc][n][32], zscL[kc][n][32]
// (n = b*1024+hw, k-slice kc*32..+31). Also zeroes the loss slot.
__global__ __launch_bounds__(256) void vq_prep(const float* __restrict__ z,
                                               unsigned short* __restrict__ zscH,
                                               unsigned short* __restrict__ zscL,
                                               float* __restrict__ loss_slot)
{
    __shared__ unsigned lzp[64][68];          // packed hi|lo<<16, 64 px x 64 k slab

    const int t  = threadIdx.x;
    const int n0 = blockIdx.x << 6;           // 512 blocks x 64 px
    const int bb = n0 >> 10, hw0 = n0 & 1023;
    if (blockIdx.x == 0 && t == 0) *loss_slot = 0.0f;
    const float* zb = z + (size_t)bb * (EDIM * HWSZ) + hw0;

    for (int pk = 0; pk < 4; ++pk) {          // 4 k-slabs of 64
#pragma unroll
        for (int i = 0; i < 4; ++i) {         // 64k x 64px = 1024 float4
            const int linear = (i << 8) + t;
            const int kk  = linear >> 4;
            const int px4 = (linear & 15) << 2;
            const float4 v = *reinterpret_cast<const float4*>(zb + (pk * 64 + kk) * HWSZ + px4);
            const float vv[4] = {v.x, v.y, v.z, v.w};
#pragma unroll
            for (int j = 0; j < 4; ++j) {
                const unsigned short h = f2bf(vv[j]);
                const unsigned short l = f2bf(vv[j] - bf2f(h));
                lzp[px4 + j][kk] = (unsigned)h | ((unsigned)l << 16);
            }
        }
        __syncthreads();
        {
            const int px = t >> 2, q = t & 3;
            const int kq16 = q << 4;                      // 16 k per thread
            const uint4 q0 = *(const uint4*)&lzp[px][kq16];
            const uint4 q1 = *(const uint4*)&lzp[px][kq16 + 4];
            const uint4 q2 = *(const uint4*)&lzp[px][kq16 + 8];
            const uint4 q3 = *(const uint4*)&lzp[px][kq16 + 12];
            #define PH(a,b) (((a) & 0xffffu) | ((b) << 16))
            #define PL(a,b) (((a) >> 16) | ((b) & 0xffff0000u))
            const uint4 hA = {PH(q0.x,q0.y), PH(q0.z,q0.w), PH(q1.x,q1.y), PH(q1.z,q1.w)};
            const uint4 hB = {PH(q2.x,q2.y), PH(q2.z,q2.w), PH(q3.x,q3.y), PH(q3.z,q3.w)};
            const uint4 lA = {PL(q0.x,q0.y), PL(q0.z,q0.w), PL(q1.x,q1.y), PL(q1.z,q1.w)};
            const uint4 lB = {PL(q2.x,q2.y), PL(q2.z,q2.w), PL(q3.x,q3.y), PL(q3.z,q3.w)};
            #undef PH
            #undef PL
            const int kc  = (pk << 1) + (q >> 1);         // k-chunk of 32
            const size_t off = ((size_t)kc * NPIX + n0 + px) * 32 + ((q & 1) << 4);
            *(uint4*)(zscH + off)     = hA;               // k sub-slice 0..7 of half
            *(uint4*)(zscH + off + 8) = hB;               // k sub-slice 8..15
            *(uint4*)(zscL + off)     = lA;
            *(uint4*)(zscL + off + 8) = lB;
        }
        __syncthreads();
    }
}

// ---------------------------------------------------------------------------
// Kernel 2: MFMA distance GEMM + exact argmin. Block = 256 thr (4 waves) x
// 64 px x 1024 codes. z in LDS (staged once, read-only); codebook A-frags
// stream global->VGPR double-buffered; no main-loop barriers.
__global__ __launch_bounds__(256, 2) void vq_argmin_g(
    const float* __restrict__ z, const float* __restrict__ cb,
    const unsigned short* __restrict__ zscH, const unsigned short* __restrict__ zscL,
    const unsigned short* __restrict__ cbs, const float* __restrict__ cnorm,
    float* __restrict__ idx_out)
{
    __shared__ unsigned short zh[8][64][32];     // 32 KiB
    __shared__ unsigned short zl[8][64][32];     // 32 KiB
    __shared__ float cn[NCODE];                  // 4 KiB
    __shared__ float rb1[4][64], rb2[4][64];
    __shared__ int   ri1[4][64], ri2[4][64];
    __shared__ int   fl_cnt, fl_px[64], fl_i1[64], fl_i2[64];
    __shared__ float fred[2][4];

    const int t    = threadIdx.x;
    const int lane = t & 63;
    const int w    = t >> 6;
    const int n0   = blockIdx.x << 6;            // 512 blocks
    const int bb   = n0 >> 10, hw0 = n0 & 1023;
    const int l15  = lane & 15, kq = lane >> 4;

    // ---- prologue: stage z planes (32 KB each, coalesced 16B/lane) + cn
#pragma unroll
    for (int i = 0; i < 8; ++i) {
        const int idx = (i << 8) + t;            // 0..2047 uint4 slots
        const int kc  = idx >> 8;
        const int px  = (idx & 255) >> 2;
        const int q   = idx & 3;
        const size_t so = ((size_t)kc * NPIX + n0 + px) * 32 + (q << 3);
        *(uint4*)&zh[kc][px][q << 3] = *(const uint4*)(zscH + so);
        *(uint4*)&zl[kc][px][q << 3] = *(const uint4*)(zscL + so);
    }
#pragma unroll
    for (int i = 0; i < 4; ++i) cn[(i << 8) + t] = cnorm[(i << 8) + t];
    if (t == 0) fl_cnt = 0;
    __syncthreads();

    float b1[4], b2[4]; int i1[4], i2[4];
#pragma unroll
    for (int nf = 0; nf < 4; ++nf) { b1[nf] = 3.402823e38f; b2[nf] = 3.402823e38f; i1[nf] = 0; i2[nf] = 0; }

    f32x4 acc[4][4];
    const size_t lanebase = ((size_t)((w << 6) + l15) << 6) + (kq << 3);

    s16x8 pA0, pA1, pA2, pA3, pA4, pA5, pA6, pA7;   // A frags: hi mf0..3, lo mf0..3
    s16x8 pB0, pB1, pB2, pB3, pB4, pB5, pB6, pB7;

    // LOADA: 8 global 16-B frag loads for flat step S (g = S>>3, kc = S&7).
#define LOADA(d0,d1,d2,d3,d4,d5,d6,d7,S) do {                                   \
        const int g_ = (S) >> 3, kc_ = (S) & 7;                                 \
        const unsigned short* bp = cbs +                                        \
            (((size_t)kc_ * NCODE + (g_ << 8)) << 6) + lanebase;                \
        d0 = *(const s16x8*)(bp);          d1 = *(const s16x8*)(bp + 1024);     \
        d2 = *(const s16x8*)(bp + 2048);   d3 = *(const s16x8*)(bp + 3072);     \
        d4 = *(const s16x8*)(bp + 32);     d5 = *(const s16x8*)(bp + 1056);     \
        d6 = *(const s16x8*)(bp + 2080);   d7 = *(const s16x8*)(bp + 3104);     \
    } while (0)

    // COMPUTE: z frag LDS reads + 48 MFMA + (kc==7) top-2 for flat step S.
#define COMPUTE(a0,a1,a2,a3,a4,a5,a6,a7,S) do {                                 \
        const int g_ = (S) >> 3, kc_ = (S) & 7;                                 \
        if (kc_ == 0) {                                                         \
            _Pragma("unroll") for (int mf = 0; mf < 4; ++mf)                    \
            _Pragma("unroll") for (int nf = 0; nf < 4; ++nf)                    \
                acc[mf][nf] = (f32x4){0.f, 0.f, 0.f, 0.f};                      \
        }                                                                       \
        s16x8 bh[4], bl[4];                                                     \
        _Pragma("unroll") for (int nf = 0; nf < 4; ++nf) {                      \
            bh[nf] = *(const s16x8*)&zh[kc_][(nf << 4) + l15][kq << 3];         \
            bl[nf] = *(const s16x8*)&zl[kc_][(nf << 4) + l15][kq << 3];         \
        }                                                                       \
        _Pragma("unroll") for (int nf = 0; nf < 4; ++nf) {                      \
            acc[0][nf] = __builtin_amdgcn_mfma_f32_16x16x32_bf16(a0, bh[nf], acc[0][nf], 0, 0, 0); \
            acc[1][nf] = __builtin_amdgcn_mfma_f32_16x16x32_bf16(a1, bh[nf], acc[1][nf], 0, 0, 0); \
            acc[2][nf] = __builtin_amdgcn_mfma_f32_16x16x32_bf16(a2, bh[nf], acc[2][nf], 0, 0, 0); \
            acc[3][nf] = __builtin_amdgcn_mfma_f32_16x16x32_bf16(a3, bh[nf], acc[3][nf], 0, 0, 0); \
        }                                                                       \
        _Pragma("unroll") for (int nf = 0; nf < 4; ++nf) {                      \
            acc[0][nf] = __builtin_amdgcn_mfma_f32_16x16x32_bf16(a0, bl[nf], acc[0][nf], 0, 0, 0); \
            acc[1][nf] = __builtin_amdgcn_mfma_f32_16x16x32_bf16(a1, bl[nf], acc[1][nf], 0, 0, 0); \
            acc[2][nf] = __builtin_amdgcn_mfma_f32_16x16x32_bf16(a2, bl[nf], acc[2][nf], 0, 0, 0); \
            acc[3][nf] = __builtin_amdgcn_mfma_f32_16x16x32_bf16(a3, bl[nf], acc[3][nf], 0, 0, 0); \
        }                                                                       \
        _Pragma("unroll") for (int nf = 0; nf < 4; ++nf) {                      \
            acc[0][nf] = __builtin_amdgcn_mfma_f32_16x16x32_bf16(a4, bh[nf], acc[0][nf], 0, 0, 0); \
            acc[1][nf] = __builtin_amdgcn_mfma_f32_16x16x32_bf16(a5, bh[nf], acc[1][nf], 0, 0, 0); \
            acc[2][nf] = __builtin_amdgcn_mfma_f32_16x16x32_bf16(a6, bh[nf], acc[2][nf], 0, 0, 0); \
            acc[3][nf] = __builtin_amdgcn_mfma_f32_16x16x32_bf16(a7, bh[nf], acc[3][nf], 0, 0, 0); \
        }                                                                       \
        if (kc_ == 7) {                                                         \
            _Pragma("unroll") for (int mf = 0; mf < 4; ++mf)                    \
            _Pragma("unroll") for (int r = 0; r < 4; ++r) {                     \
                const int local = (w << 6) + (mf << 4) + (kq << 2) + r;         \
                const int code  = (g_ << 8) + local;                            \
                const float cnv = cn[code];                                     \
                _Pragma("unroll") for (int nf = 0; nf < 4; ++nf) {              \
                    const float d = fmaf(-2.f, acc[mf][nf][r], cnv);            \
                    if (d < b1[nf])      { b2[nf] = b1[nf]; i2[nf] = i1[nf]; b1[nf] = d; i1[nf] = code; } \
                    else if (d < b2[nf]) { b2[nf] = d; i2[nf] = code; }         \
                }                                                               \
            }                                                                   \
        }                                                                       \
    } while (0)

    LOADA(pA0,pA1,pA2,pA3,pA4,pA5,pA6,pA7, 0);
    for (int s = 0; s < 32; s += 2) {
        LOADA(pB0,pB1,pB2,pB3,pB4,pB5,pB6,pB7, s + 1);
        COMPUTE(pA0,pA1,pA2,pA3,pA4,pA5,pA6,pA7, s);
        if (s + 2 < 32) LOADA(pA0,pA1,pA2,pA3,pA4,pA5,pA6,pA7, s + 2);
        COMPUTE(pB0,pB1,pB2,pB3,pB4,pB5,pB6,pB7, s + 1);
    }
#undef LOADA
#undef COMPUTE

    // ---- cross-lane merge (lanes p, p+16, p+32, p+48 share pixel col p)
#pragma unroll
    for (int nf = 0; nf < 4; ++nf) {
        float B1 = b1[nf], B2 = b2[nf]; int I1 = i1[nf], I2 = i2[nf];
#pragma unroll
        for (int m = 16; m <= 32; m <<= 1) {
            const float ob1 = __shfl_xor(B1, m, 64), ob2 = __shfl_xor(B2, m, 64);
            const int   oi1 = __shfl_xor(I1, m, 64), oi2 = __shfl_xor(I2, m, 64);
            if (ob1 < B1 || (ob1 == B1 && oi1 < I1)) {
                if (B1 < ob2 || (B1 == ob2 && I1 < oi2)) { B2 = B1; I2 = I1; }
                else                                      { B2 = ob2; I2 = oi2; }
                B1 = ob1; I1 = oi1;
            } else if (ob1 < B2 || (ob1 == B2 && oi1 < I2)) { B2 = ob1; I2 = oi1; }
        }
        if (lane < 16) {
            const int px = (nf << 4) + lane;
            rb1[w][px] = B1; rb2[w][px] = B2; ri1[w][px] = I1; ri2[w][px] = I2;
        }
    }
    __syncthreads();
    if (t < 64) {
        float B1 = rb1[0][t], B2 = rb2[0][t]; int I1 = ri1[0][t], I2 = ri2[0][t];
#pragma unroll
        for (int ww = 1; ww < 4; ++ww) {
            const float ob1 = rb1[ww][t], ob2 = rb2[ww][t];
            const int   oi1 = ri1[ww][t], oi2 = ri2[ww][t];
            if (ob1 < B1 || (ob1 == B1 && oi1 < I1)) {
                if (B1 < ob2 || (B1 == ob2 && I1 < oi2)) { B2 = B1; I2 = I1; }
                else                                      { B2 = ob2; I2 = oi2; }
                B1 = ob1; I1 = oi1;
            } else if (ob1 < B2 || (ob1 == B2 && oi1 < I2)) { B2 = ob1; I2 = oi1; }
        }
        if (B2 - B1 > THR) idx_out[n0 + t] = (float)I1;   // provably exact
        else {
            const int pos = atomicAdd(&fl_cnt, 1);
            fl_px[pos] = t; fl_i1[pos] = I1; fl_i2[pos] = I2;
        }
    }
    __syncthreads();
    // ---- exact fp32 fallback for near-tie pixels (expected ~1-2 per block)
    const int nfl = fl_cnt;
    for (int fi = 0; fi < nfl; ++fi) {
        const int px = fl_px[fi], ia = fl_i1[fi], ib = fl_i2[fi];
        const float zk = z[(size_t)bb * (EDIM * HWSZ) + t * HWSZ + hw0 + px];  // k = t
        const float da = zk - cb[(size_t)ia * EDIM + t];
        const float db = zk - cb[(size_t)ib * EDIM + t];
        float s1 = da * da, s2 = db * db;
#pragma unroll
        for (int m = 32; m; m >>= 1) { s1 += __shfl_xor(s1, m, 64); s2 += __shfl_xor(s2, m, 64); }
        if (lane == 0) { fred[0][w] = s1; fred[1][w] = s2; }
        __syncthreads();
        if (t == 0) {
            const float d1 = fred[0][0] + fred[0][1] + fred[0][2] + fred[0][3];
            const float d2 = fred[1][0] + fred[1][1] + fred[1][2] + fred[1][3];
            const int win = (d2 < d1 || (d2 == d1 && ib < ia)) ? ib : ia;
            idx_out[n0 + px] = (float)win;
        }
        __syncthreads();
    }
}

// ---------------------------------------------------------------------------
// Kernel 3: gather z_q = codebook[idx], transpose-store to (B,C,H,W), fused
// MSE loss: codebook_loss = (1 + BETA) * mean((z_q - z)^2), BETA = 0.25.
__global__ __launch_bounds__(256) void vq_gather(const float* __restrict__ z,
                                                 const float* __restrict__ cb,
                                                 const float* __restrict__ idxf,
                                                 float* __restrict__ out)
{
    __shared__ float lq[64][129];
    __shared__ int   sidx[64];

    const int t   = threadIdx.x;
    const int n0  = blockIdx.x << 6;
    const int bb  = n0 >> 10;
    const int hw0 = n0 & 1023;

    if (t < 64) sidx[t] = (int)idxf[n0 + t];

    const float* zb = z   + (size_t)bb * (EDIM * HWSZ) + hw0;
    float*       ob = out + (size_t)bb * (EDIM * HWSZ) + hw0;
    const int p  = t & 63;
    const int cq = t >> 6;
    float sum = 0.0f;

    for (int h = 0; h < 2; ++h) {
        __syncthreads();
#pragma unroll
        for (int i = 0; i < 8; ++i) {
            const int linear = (i << 8) + t;
            const int pr = linear >> 5;
            const int f4 = (linear & 31) << 2;
            const float4 v = *reinterpret_cast<const float4*>(
                cb + (size_t)sidx[pr] * EDIM + (h << 7) + f4);
            float* dst = &lq[pr][f4];
            dst[0] = v.x; dst[1] = v.y; dst[2] = v.z; dst[3] = v.w;
        }
        __syncthreads();
#pragma unroll 4
        for (int r = 0; r < 32; ++r) {
            const int c  = (r << 2) + cq;
            const int cf = (h << 7) + c;
            const float q  = lq[p][c];
            const float zv = zb[cf * HWSZ + p];
            ob[cf * HWSZ + p] = q;
            const float dd = q - zv;
            sum = fmaf(dd, dd, sum);
        }
    }

#pragma unroll
    for (int m = 32; m; m >>= 1) sum += __shfl_xor(sum, m, 64);
    if (p == 0) atomicAdd(out + LOSS_OFF, sum * (1.25f / 8388608.0f));
}

// ---------------------------------------------------------------------------
extern "C" void kernel_launch(void* const* d_in, const int* in_sizes, int n_in,
                              void* d_out, int out_size, void* d_ws, size_t ws_size,
                              hipStream_t stream)
{
    const float* z  = (const float*)d_in[0];
    const float* cb = (const float*)d_in[1];
    float* out = (float*)d_out;
    // z bf16 planes parked in the z_q region (16.78 MB each, exact byte fit);
    // consumed by vq_argmin_g, then overwritten by vq_gather.
    unsigned short* zscH = (unsigned short*)out;
    unsigned short* zscL = zscH + (size_t)8 * NPIX * 32;
    // d_ws: cbs (1 MB) | cnorm (4 KB) — requirement proven present in rounds 6-7.
    unsigned short* cbs = (unsigned short*)d_ws;
    float*          cnp = (float*)(cbs + (size_t)8 * NCODE * 64);

    vq_cbsplit <<<NCODE / 8, 256, 0, stream>>>(cb, cbs, cnp);
    vq_prep    <<<NPIX / 64, 256, 0, stream>>>(z, zscH, zscL, out + LOSS_OFF);
    vq_argmin_g<<<NPIX / 64, 256, 0, stream>>>(z, cb, zscH, zscL, cbs, cnp, out + IDX_OFF);
    vq_gather  <<<NPIX / 64, 256, 0, stream>>>(z, cb, out + IDX_OFF, out);
}

// Round 9
// 168.403 us; speedup vs baseline: 2.0345x; 1.2081x over previous
//
#include <hip/hip_runtime.h>

// VQ-VAE vector quantization for z:(32,256,32,32) f32, codebook:(1024,256) f32.
// Outputs (flat f32 in d_out): z_q (B,C,H,W) [8388608] | loss [1] | indices as float [32768].
//
// Round 9: mega-fusion + coalesced cb planes.
//   - r8 post-mortem: argmin core 87us (MfmaUtil 24% = exact floor arithmetic);
//     combined-row cbs made every A-frag load touch 16 half-used 128B lines.
//     Fix: split cbsH/cbsL planes (64B rows) -> each wave load = contiguous 1KB.
//   - prep and gather FUSED into the argmin kernel (same 64-px block decomposition):
//     z converted f32->hi/lo bf16 straight into LDS (no 67MB zsc round-trip),
//     gather/loss phase reuses zh LDS as staging for cb[winner] rows.
//   - 2 kernels total: cbsplit (also zeroes loss), vq_mega.
// Argmin core (top-2, merges, exact-fp32 fallback) verbatim from r8 (passed).

#define EDIM   256
#define NCODE  1024
#define HWSZ   1024
#define NPIX   32768
#define LOSS_OFF 8388608
#define IDX_OFF  8388609
#define THR    0.05f

typedef __attribute__((ext_vector_type(8))) short s16x8;   // 8 bf16 = 4 VGPR (MFMA A/B frag)
typedef __attribute__((ext_vector_type(4))) float f32x4;   // MFMA C/D frag

__device__ inline unsigned short f2bf(float f) {           // RNE f32 -> bf16
    unsigned u = __float_as_uint(f);
    return (unsigned short)((u + 0x7FFFu + ((u >> 16) & 1u)) >> 16);
}
__device__ inline float bf2f(unsigned short h) { return __uint_as_float(((unsigned)h) << 16); }

// ---------------------------------------------------------------------------
// Kernel 0: one-time codebook split -> SEPARATE planes cbsH/cbsL[kc][code][32]
// (64-B rows: wave frag loads are contiguous 1 KB). + exact f32 norms + loss=0.
__global__ __launch_bounds__(256) void vq_cbsplit(const float* __restrict__ cb,
                                                  unsigned short* __restrict__ cbsH,
                                                  unsigned short* __restrict__ cbsL,
                                                  float* __restrict__ cnorm,
                                                  float* __restrict__ loss_slot)
{
    const int t    = threadIdx.x;
    const int code = (blockIdx.x << 3) + (t >> 5);
    const int kg   = t & 31;                  // k = kg*8 .. kg*8+7
    if (blockIdx.x == 0 && t == 0) *loss_slot = 0.0f;
    const float4 v0 = *(const float4*)(cb + (size_t)code * EDIM + (kg << 3));
    const float4 v1 = *(const float4*)(cb + (size_t)code * EDIM + (kg << 3) + 4);

    float s = v0.x*v0.x + v0.y*v0.y + v0.z*v0.z + v0.w*v0.w
            + v1.x*v1.x + v1.y*v1.y + v1.z*v1.z + v1.w*v1.w;
    s += __shfl_xor(s, 1, 64);  s += __shfl_xor(s, 2, 64);
    s += __shfl_xor(s, 4, 64);  s += __shfl_xor(s, 8, 64);
    s += __shfl_xor(s, 16, 64);                 // sum over the code's 32 lanes
    if (kg == 0) cnorm[code] = s;

    const float f[8] = {v0.x, v0.y, v0.z, v0.w, v1.x, v1.y, v1.z, v1.w};
    unsigned short h[8], l[8];
#pragma unroll
    for (int j = 0; j < 8; ++j) { h[j] = f2bf(f[j]); l[j] = f2bf(f[j] - bf2f(h[j])); }
    uint4 H, L;
    H.x = (unsigned)h[0] | ((unsigned)h[1] << 16);  H.y = (unsigned)h[2] | ((unsigned)h[3] << 16);
    H.z = (unsigned)h[4] | ((unsigned)h[5] << 16);  H.w = (unsigned)h[6] | ((unsigned)h[7] << 16);
    L.x = (unsigned)l[0] | ((unsigned)l[1] << 16);  L.y = (unsigned)l[2] | ((unsigned)l[3] << 16);
    L.z = (unsigned)l[4] | ((unsigned)l[5] << 16);  L.w = (unsigned)l[6] | ((unsigned)l[7] << 16);
    const size_t off = ((size_t)(kg >> 2) * NCODE + code) * 32 + ((size_t)(kg & 3) << 3);
    *(uint4*)(cbsH + off) = H;
    *(uint4*)(cbsL + off) = L;
}

// ---------------------------------------------------------------------------
// Kernel 1: fused prep + MFMA argmin + gather/loss. Block = 256 thr (4 waves)
// x 64 px x 1024 codes. z converted to hi/lo bf16 in LDS (prologue); cb A-frags
// stream global->VGPR (coalesced 1KB/wave-instr, double-buffered, no barriers
// in main loop); epilogue gathers cb[winner] -> z_q + fused MSE loss.
__global__ __launch_bounds__(256, 2) void vq_mega(
    const float* __restrict__ z, const float* __restrict__ cb,
    const unsigned short* __restrict__ cbsH, const unsigned short* __restrict__ cbsL,
    const float* __restrict__ cnorm, float* __restrict__ out)
{
    __shared__ unsigned short zh[8][64][32];     // 32 KiB (aliased as lq in gather)
    __shared__ unsigned short zl[8][64][32];     // 32 KiB
    __shared__ float cn[NCODE];                  // 4 KiB
    __shared__ float rb1[4][64], rb2[4][64];
    __shared__ int   ri1[4][64], ri2[4][64];
    __shared__ int   fl_cnt, fl_px[64], fl_i1[64], fl_i2[64];
    __shared__ float fred[2][4];
    __shared__ int   sidx[64];

    const int t    = threadIdx.x;
    const int lane = t & 63;
    const int w    = t >> 6;
    const int n0   = blockIdx.x << 6;            // 512 blocks
    const int bb   = n0 >> 10, hw0 = n0 & 1023;
    const int l15  = lane & 15, kq = lane >> 4;

    const float* zb = z   + (size_t)bb * (EDIM * HWSZ) + hw0;
    float*       ob = out + (size_t)bb * (EDIM * HWSZ) + hw0;

    // ---- prologue: z f32 -> hi/lo bf16 straight into LDS (one-time)
#pragma unroll 4
    for (int i = 0; i < 16; ++i) {
        const int linear = (i << 8) + t;         // 0..4095
        const int c   = linear >> 4;             // channel 0..255
        const int px4 = (linear & 15) << 2;      // pixel 0..60 step 4
        const float4 v = *(const float4*)(zb + c * HWSZ + px4);
        const float vv[4] = {v.x, v.y, v.z, v.w};
        const int kc = c >> 5, ko = c & 31;
#pragma unroll
        for (int j = 0; j < 4; ++j) {
            const unsigned short h = f2bf(vv[j]);
            const unsigned short l = f2bf(vv[j] - bf2f(h));
            zh[kc][px4 + j][ko] = h;
            zl[kc][px4 + j][ko] = l;
        }
    }
#pragma unroll
    for (int i = 0; i < 4; ++i) cn[(i << 8) + t] = cnorm[(i << 8) + t];
    if (t == 0) fl_cnt = 0;
    __syncthreads();

    float b1[4], b2[4]; int i1[4], i2[4];
#pragma unroll
    for (int nf = 0; nf < 4; ++nf) { b1[nf] = 3.402823e38f; b2[nf] = 3.402823e38f; i1[nf] = 0; i2[nf] = 0; }

    f32x4 acc[4][4];
    const size_t lanebase = ((size_t)((w << 6) + l15) << 5) + (kq << 3);

    s16x8 pA0, pA1, pA2, pA3, pA4, pA5, pA6, pA7;   // A frags: hi mf0..3, lo mf0..3
    s16x8 pB0, pB1, pB2, pB3, pB4, pB5, pB6, pB7;

    // LOADA: 8 coalesced 16-B frag loads for flat step S (g = S>>3, kc = S&7).
#define LOADA(d0,d1,d2,d3,d4,d5,d6,d7,S) do {                                   \
        const int g_ = (S) >> 3, kc_ = (S) & 7;                                 \
        const size_t tb = (((size_t)kc_ * NCODE + (g_ << 8)) << 5) + lanebase;  \
        const unsigned short* bpH = cbsH + tb;                                  \
        const unsigned short* bpL = cbsL + tb;                                  \
        d0 = *(const s16x8*)(bpH);         d1 = *(const s16x8*)(bpH + 512);     \
        d2 = *(const s16x8*)(bpH + 1024);  d3 = *(const s16x8*)(bpH + 1536);    \
        d4 = *(const s16x8*)(bpL);         d5 = *(const s16x8*)(bpL + 512);     \
        d6 = *(const s16x8*)(bpL + 1024);  d7 = *(const s16x8*)(bpL + 1536);    \
    } while (0)

    // COMPUTE: z frag LDS reads + 48 MFMA + (kc==7) top-2 for flat step S.
#define COMPUTE(a0,a1,a2,a3,a4,a5,a6,a7,S) do {                                 \
        const int g_ = (S) >> 3, kc_ = (S) & 7;                                 \
        if (kc_ == 0) {                                                         \
            _Pragma("unroll") for (int mf = 0; mf < 4; ++mf)                    \
            _Pragma("unroll") for (int nf = 0; nf < 4; ++nf)                    \
                acc[mf][nf] = (f32x4){0.f, 0.f, 0.f, 0.f};                      \
        }                                                                       \
        s16x8 bh[4], bl[4];                                                     \
        _Pragma("unroll") for (int nf = 0; nf < 4; ++nf) {                      \
            bh[nf] = *(const s16x8*)&zh[kc_][(nf << 4) + l15][kq << 3];         \
            bl[nf] = *(const s16x8*)&zl[kc_][(nf << 4) + l15][kq << 3];         \
        }                                                                       \
        _Pragma("unroll") for (int nf = 0; nf < 4; ++nf) {                      \
            acc[0][nf] = __builtin_amdgcn_mfma_f32_16x16x32_bf16(a0, bh[nf], acc[0][nf], 0, 0, 0); \
            acc[1][nf] = __builtin_amdgcn_mfma_f32_16x16x32_bf16(a1, bh[nf], acc[1][nf], 0, 0, 0); \
            acc[2][nf] = __builtin_amdgcn_mfma_f32_16x16x32_bf16(a2, bh[nf], acc[2][nf], 0, 0, 0); \
            acc[3][nf] = __builtin_amdgcn_mfma_f32_16x16x32_bf16(a3, bh[nf], acc[3][nf], 0, 0, 0); \
        }                                                                       \
        _Pragma("unroll") for (int nf = 0; nf < 4; ++nf) {                      \
            acc[0][nf] = __builtin_amdgcn_mfma_f32_16x16x32_bf16(a0, bl[nf], acc[0][nf], 0, 0, 0); \
            acc[1][nf] = __builtin_amdgcn_mfma_f32_16x16x32_bf16(a1, bl[nf], acc[1][nf], 0, 0, 0); \
            acc[2][nf] = __builtin_amdgcn_mfma_f32_16x16x32_bf16(a2, bl[nf], acc[2][nf], 0, 0, 0); \
            acc[3][nf] = __builtin_amdgcn_mfma_f32_16x16x32_bf16(a3, bl[nf], acc[3][nf], 0, 0, 0); \
        }                                                                       \
        _Pragma("unroll") for (int nf = 0; nf < 4; ++nf) {                      \
            acc[0][nf] = __builtin_amdgcn_mfma_f32_16x16x32_bf16(a4, bh[nf], acc[0][nf], 0, 0, 0); \
            acc[1][nf] = __builtin_amdgcn_mfma_f32_16x16x32_bf16(a5, bh[nf], acc[1][nf], 0, 0, 0); \
            acc[2][nf] = __builtin_amdgcn_mfma_f32_16x16x32_bf16(a6, bh[nf], acc[2][nf], 0, 0, 0); \
            acc[3][nf] = __builtin_amdgcn_mfma_f32_16x16x32_bf16(a7, bh[nf], acc[3][nf], 0, 0, 0); \
        }                                                                       \
        if (kc_ == 7) {                                                         \
            _Pragma("unroll") for (int mf = 0; mf < 4; ++mf)                    \
            _Pragma("unroll") for (int r = 0; r < 4; ++r) {                     \
                const int local = (w << 6) + (mf << 4) + (kq << 2) + r;         \
                const int code  = (g_ << 8) + local;                            \
                const float cnv = cn[code];                                     \
                _Pragma("unroll") for (int nf = 0; nf < 4; ++nf) {              \
                    const float d = fmaf(-2.f, acc[mf][nf][r], cnv);            \
                    if (d < b1[nf])      { b2[nf] = b1[nf]; i2[nf] = i1[nf]; b1[nf] = d; i1[nf] = code; } \
                    else if (d < b2[nf]) { b2[nf] = d; i2[nf] = code; }         \
                }                                                               \
            }                                                                   \
        }                                                                       \
    } while (0)

    LOADA(pA0,pA1,pA2,pA3,pA4,pA5,pA6,pA7, 0);
    for (int s = 0; s < 32; s += 2) {
        LOADA(pB0,pB1,pB2,pB3,pB4,pB5,pB6,pB7, s + 1);
        COMPUTE(pA0,pA1,pA2,pA3,pA4,pA5,pA6,pA7, s);
        if (s + 2 < 32) LOADA(pA0,pA1,pA2,pA3,pA4,pA5,pA6,pA7, s + 2);
        COMPUTE(pB0,pB1,pB2,pB3,pB4,pB5,pB6,pB7, s + 1);
    }
#undef LOADA
#undef COMPUTE

    // ---- cross-lane merge (lanes p, p+16, p+32, p+48 share pixel col p)
#pragma unroll
    for (int nf = 0; nf < 4; ++nf) {
        float B1 = b1[nf], B2 = b2[nf]; int I1 = i1[nf], I2 = i2[nf];
#pragma unroll
        for (int m = 16; m <= 32; m <<= 1) {
            const float ob1 = __shfl_xor(B1, m, 64), ob2 = __shfl_xor(B2, m, 64);
            const int   oi1 = __shfl_xor(I1, m, 64), oi2 = __shfl_xor(I2, m, 64);
            if (ob1 < B1 || (ob1 == B1 && oi1 < I1)) {
                if (B1 < ob2 || (B1 == ob2 && I1 < oi2)) { B2 = B1; I2 = I1; }
                else                                      { B2 = ob2; I2 = oi2; }
                B1 = ob1; I1 = oi1;
            } else if (ob1 < B2 || (ob1 == B2 && oi1 < I2)) { B2 = ob1; I2 = oi1; }
        }
        if (lane < 16) {
            const int px = (nf << 4) + lane;
            rb1[w][px] = B1; rb2[w][px] = B2; ri1[w][px] = I1; ri2[w][px] = I2;
        }
    }
    __syncthreads();
    if (t < 64) {
        float B1 = rb1[0][t], B2 = rb2[0][t]; int I1 = ri1[0][t], I2 = ri2[0][t];
#pragma unroll
        for (int ww = 1; ww < 4; ++ww) {
            const float ob1 = rb1[ww][t], ob2 = rb2[ww][t];
            const int   oi1 = ri1[ww][t], oi2 = ri2[ww][t];
            if (ob1 < B1 || (ob1 == B1 && oi1 < I1)) {
                if (B1 < ob2 || (B1 == ob2 && I1 < oi2)) { B2 = B1; I2 = I1; }
                else                                      { B2 = ob2; I2 = oi2; }
                B1 = ob1; I1 = oi1;
            } else if (ob1 < B2 || (ob1 == B2 && oi1 < I2)) { B2 = ob1; I2 = oi1; }
        }
        if (B2 - B1 > THR) {                     // provably exact
            out[IDX_OFF + n0 + t] = (float)I1;
            sidx[t] = I1;
        } else {
            const int pos = atomicAdd(&fl_cnt, 1);
            fl_px[pos] = t; fl_i1[pos] = I1; fl_i2[pos] = I2;
        }
    }
    __syncthreads();
    // ---- exact fp32 fallback for near-tie pixels (expected ~1-2 per block)
    const int nfl = fl_cnt;
    for (int fi = 0; fi < nfl; ++fi) {
        const int px = fl_px[fi], ia = fl_i1[fi], ib = fl_i2[fi];
        const float zk = z[(size_t)bb * (EDIM * HWSZ) + t * HWSZ + hw0 + px];  // k = t
        const float da = zk - cb[(size_t)ia * EDIM + t];
        const float db = zk - cb[(size_t)ib * EDIM + t];
        float s1 = da * da, s2 = db * db;
#pragma unroll
        for (int m = 32; m; m >>= 1) { s1 += __shfl_xor(s1, m, 64); s2 += __shfl_xor(s2, m, 64); }
        if (lane == 0) { fred[0][w] = s1; fred[1][w] = s2; }
        __syncthreads();
        if (t == 0) {
            const float d1 = fred[0][0] + fred[0][1] + fred[0][2] + fred[0][3];
            const float d2 = fred[1][0] + fred[1][1] + fred[1][2] + fred[1][3];
            const int win = (d2 < d1 || (d2 == d1 && ib < ia)) ? ib : ia;
            out[IDX_OFF + n0 + px] = (float)win;
            sidx[px] = win;
        }
        __syncthreads();
    }

    // ---- fused gather + loss: z_q = cb[sidx], transposed store, MSE.
    // Stage 64-c chunks of the 64 winner rows in lq (aliases zh: 16.6 < 32 KB).
    float* lqf = (float*)&zh[0][0][0];           // [64][65]
    const int p  = t & 63;
    const int cq = t >> 6;
    float sum = 0.0f;

    for (int h4 = 0; h4 < 4; ++h4) {             // four 64-channel chunks
        __syncthreads();                         // lq free (prev chunk / argmin done)
#pragma unroll
        for (int i = 0; i < 4; ++i) {            // stage 64 rows x 64 floats
            const int linear = (i << 8) + t;
            const int pr = linear >> 4;          // winner row 0..63
            const int f4 = (linear & 15) << 2;
            const float4 v = *(const float4*)(
                cb + (size_t)sidx[pr] * EDIM + (h4 << 6) + f4);
            float* dst = &lqf[pr * 65 + f4];     // stride 65: conflict-spread
            dst[0] = v.x; dst[1] = v.y; dst[2] = v.z; dst[3] = v.w;
        }
        __syncthreads();
#pragma unroll 4
        for (int r = 0; r < 16; ++r) {           // coalesced stores: 64 consecutive hw
            const int c  = (r << 2) + cq;
            const int cf = (h4 << 6) + c;
            const float q  = lqf[p * 65 + c];
            const float zv = zb[cf * HWSZ + p];
            ob[cf * HWSZ + p] = q;
            const float dd = q - zv;
            sum = fmaf(dd, dd, sum);
        }
    }
#pragma unroll
    for (int m = 32; m; m >>= 1) sum += __shfl_xor(sum, m, 64);
    if (lane == 0) atomicAdd(out + LOSS_OFF, sum * (1.25f / 8388608.0f));
}

// ---------------------------------------------------------------------------
extern "C" void kernel_launch(void* const* d_in, const int* in_sizes, int n_in,
                              void* d_out, int out_size, void* d_ws, size_t ws_size,
                              hipStream_t stream)
{
    const float* z  = (const float*)d_in[0];
    const float* cb = (const float*)d_in[1];
    float* out = (float*)d_out;
    // d_ws: cbsH (512 KB) | cbsL (512 KB) | cnorm (4 KB) — availability
    // established in rounds 6-8 (same 1.05 MB requirement).
    const size_t plane = (size_t)8 * NCODE * 32;   // ushorts per plane
    unsigned short* cbsH = (unsigned short*)d_ws;
    unsigned short* cbsL = cbsH + plane;
    float*          cnp  = (float*)(cbsL + plane);

    vq_cbsplit<<<NCODE / 8, 256, 0, stream>>>(cb, cbsH, cbsL, cnp, out + LOSS_OFF);
    vq_mega   <<<NPIX / 64, 256, 0, stream>>>(z, cb, cbsH, cbsL, cnp, out);
}